// Round 20
// baseline (1212.168 us; speedup 1.0000x reference)
//
#include <hip/hip_runtime.h>
#include <math.h>

#define NS   512   // states
#define NO   1024  // observations
#define NB   64    // batch
#define TMAX 512

// 1024-thread k-split: wave w (0..15) owns k-slice [32w, 32w+32).
// Per-thread A: 32 uint4 chunks (8 fp16 k each), chunk c = j*4+n:
// output 64j+l, k = 32w+8n..+7. c 0..24 -> areg (compiler keeps ~20,
// software-pipelines the rest from L2 -- r17-proven idiom); c 25..31 -> LDS.
#define QREG 25
#define QLDS 7

typedef _Float16 h2v __attribute__((ext_vector_type(2)));

__device__ inline float wave_red_sum(float x) {
#pragma unroll
  for (int o = 32; o; o >>= 1) x += __shfl_xor(x, o, 64);
  return x;
}
__device__ inline float wave_red_max(float x) {
#pragma unroll
  for (int o = 32; o; o >>= 1) x = fmaxf(x, __shfl_xor(x, o, 64));
  return x;
}

__device__ inline float dot2u(unsigned int a, unsigned int b, float c) {
#if __has_builtin(__builtin_amdgcn_fdot2)
  return __builtin_amdgcn_fdot2(__builtin_bit_cast(h2v, a),
                                __builtin_bit_cast(h2v, b), c, false);
#else
  h2v av = __builtin_bit_cast(h2v, a), bv = __builtin_bit_cast(h2v, b);
  return c + (float)av.x * (float)bv.x + (float)av.y * (float)bv.y;
#endif
}

// P1: pi softmax -> pi_sm[512]
__global__ void k_pi(const float* __restrict__ pi, float* __restrict__ pi_sm) {
  __shared__ float red[8];
  int tid = threadIdx.x;
  float v = pi[tid];
  float m = wave_red_max(v);
  if ((tid & 63) == 0) red[tid >> 6] = m;
  __syncthreads();
  m = fmaxf(fmaxf(fmaxf(red[0], red[1]), fmaxf(red[2], red[3])),
            fmaxf(fmaxf(red[4], red[5]), fmaxf(red[6], red[7])));
  float e = __expf(v - m);
  float s = wave_red_sum(e);
  __syncthreads();
  if ((tid & 63) == 0) red[tid >> 6] = s;
  __syncthreads();
  s = red[0] + red[1] + red[2] + red[3] + red[4] + red[5] + red[6] + red[7];
  pi_sm[tid] = e / s;
}

// P2: column logsumexp of A (axis 0). One block (256 thr) per column. grid 512.
__global__ void k_colLse(const float* __restrict__ A, float* __restrict__ lseA) {
  __shared__ float redm[4];
  __shared__ float reds[4];
  int k = blockIdx.x, tid = threadIdx.x;
  float a0 = A[tid * NS + k], a1 = A[(tid + 256) * NS + k];
  float m = wave_red_max(fmaxf(a0, a1));
  if ((tid & 63) == 0) redm[tid >> 6] = m;
  __syncthreads();
  m = fmaxf(fmaxf(redm[0], redm[1]), fmaxf(redm[2], redm[3]));
  float s = __expf(a0 - m) + __expf(a1 - m);
  s = wave_red_sum(s);
  if ((tid & 63) == 0) reds[tid >> 6] = s;
  __syncthreads();
  s = reds[0] + reds[1] + reds[2] + reds[3];
  if (tid == 0) lseA[k] = m + __logf(s);
}

// P3: row logsumexp of E (axis 1). One block per row. grid 512 x 256.
__global__ void k_rowLseE(const float* __restrict__ E, float* __restrict__ lseE) {
  __shared__ float red[4];
  int i = blockIdx.x, tid = threadIdx.x;
  const float* row = E + i * NO;
  float a0 = row[tid], a1 = row[tid + 256], a2 = row[tid + 512], a3 = row[tid + 768];
  float m = fmaxf(fmaxf(a0, a1), fmaxf(a2, a3));
  m = wave_red_max(m);
  if ((tid & 63) == 0) red[tid >> 6] = m;
  __syncthreads();
  m = fmaxf(fmaxf(red[0], red[1]), fmaxf(red[2], red[3]));
  float s = __expf(a0 - m) + __expf(a1 - m) + __expf(a2 - m) + __expf(a3 - m);
  s = wave_red_sum(s);
  __syncthreads();
  if ((tid & 63) == 0) red[tid >> 6] = s;
  __syncthreads();
  s = red[0] + red[1] + red[2] + red[3];
  if (tid == 0) lseE[i] = m + __logf(s);
}

// P4: pack A_exp = exp(A - lseA[col]) fp16 for the 16-way k-split layout.
// k_fwd thread t (w=t>>6, l=t&63), chunk c=j*4+n: uint4 Apk[c*1024+t] =
// output 64j+l, k = 32w+8n..+7. Word u = (c*1024+t)*4 + h packs
// k = 32w+8n+2h, +1. grid 256 x 512.
__global__ void k_pack(const float* __restrict__ A, const float* __restrict__ lseA,
                       unsigned int* __restrict__ W) {
  int u = blockIdx.x * 512 + threadIdx.x;   // [0, 131072)
  int h = u & 3;
  int ct = u >> 2;
  int t = ct & 1023;
  int c = ct >> 10;
  int j = c >> 2, n = c & 3;
  int w = t >> 6, l = t & 63;
  int i  = 64 * j + l;
  int k0 = 32 * w + 8 * n + 2 * h;
  float e0 = __expf(A[i * NS + k0]     - lseA[k0]);
  float e1 = __expf(A[i * NS + k0 + 1] - lseA[k0 + 1]);
  h2v p;
  p.x = (_Float16)e0;
  p.y = (_Float16)e1;
  W[u] = __builtin_bit_cast(unsigned int, p);
}

// Main forward: ONE block (1024 thr, 16 waves = 4 waves/SIMD) per batch.
// Rationale (r17+r19): every prior config ran 2 waves/SIMD -- minimum TLP;
// the L2 A-stream (~71 B/cy achieved) and LDS/VALU overlap are both
// latency-limited there. VGPR cap is 128 in ALL rounds, so 4 waves/SIMD
// is free. This is the r17 schedule scaled: 16-way k-split, ONE barrier
// per step, own-wave u (wave w's u-slice [32w,+32) written by its lanes
// 0..31 who own outputs 32w+lo -> no barrier on u), Pf ping-pong now
// fp16-packed (two waves fill the two halves of each u32; owner reads
// lane-consecutive conflict-free; partial ~64 magnitude, fp16 rel-err
// 5e-4 -- negligible). Deferred pow2 rescale throughout (7x absmax 0.0).
__global__ __launch_bounds__(1024, 1) void k_fwd(
    const float* __restrict__ E, const int* __restrict__ x,
    const int* __restrict__ Tlen, const float* __restrict__ pi_sm,
    const float* __restrict__ lseE, const uint4* __restrict__ Apk,
    float* __restrict__ out) {
  __shared__ uint4 Alds[QLDS * 1024];           // 112 KB
  __shared__ unsigned int Pf[2][8 * 512];       // 32 KB ping-pong fp16 pairs
  __shared__ __align__(16) uint4 ubuf[NS / 8];  // 1 KB u (fp16)
  __shared__ int xrow[TMAX];                    // 2 KB
  __shared__ __align__(16) float red[2][16];    // ping-pong sigma partials
  int b = blockIdx.x, tid = threadIdx.x;
  int w = tid >> 6, l = tid & 63;
  int lo = l & 31;
  bool owner = (l < 32);
  int i_own = 32 * w + lo;                      // owned output (if owner)

  // Prologue: chunks 0..24 -> areg (compiler tiers), 25..31 -> LDS.
  uint4 areg[QREG];
#pragma unroll
  for (int q = 0; q < QREG; q++) areg[q] = Apk[q * 1024 + tid];
#pragma unroll
  for (int q = 0; q < QLDS; q++) Alds[q * 1024 + tid] = Apk[(QREG + q) * 1024 + tid];

  for (int t2 = tid; t2 < TMAX; t2 += 1024) xrow[t2] = x[b * TMAX + t2];

  float pi_i = 0.f, lse_i = 0.f;
  const float* Erow = E;
  if (owner) {
    pi_i  = pi_sm[i_own];
    lse_i = lseE[i_own];
    Erow  = E + i_own * NO;
  }
  int Tb = Tlen[b];
  float c = 0.f;        // log2-domain accumulator
  float Dlog = 0.f;     // log2 d_{t-1}
  int gexp_prev = 19;
  int cur = 0;          // parity for Pf and red
  __syncthreads();

  for (int t = 0; t < Tb; t++) {
    int nxt = cur ^ 1;
    float epre = owner ? Erow[xrow[t]] : 0.f;   // gather early; hides under dot
    if (t) {
      // wave's 4 uniform u-chunks (k-slice [32w, 32w+32)), own-wave written
      uint4 uv0 = ubuf[4 * w + 0], uv1 = ubuf[4 * w + 1];
      uint4 uv2 = ubuf[4 * w + 2], uv3 = ubuf[4 * w + 3];
      float acc[8];
#pragma unroll
      for (int j = 0; j < 8; j++) acc[j] = 0.f;
#pragma unroll
      for (int j = 0; j < 8; j++) {
#pragma unroll
        for (int n = 0; n < 4; n++) {
          int cq = j * 4 + n;   // compile-time constant (full unroll)
          uint4 av = (cq < QREG) ? areg[cq] : Alds[(cq - QREG) * 1024 + tid];
          uint4 uv = (n == 0) ? uv0 : (n == 1) ? uv1 : (n == 2) ? uv2 : uv3;
          acc[j] = dot2u(av.x, uv.x, acc[j]);
          acc[j] = dot2u(av.y, uv.y, acc[j]);
          acc[j] = dot2u(av.z, uv.z, acc[j]);
          acc[j] = dot2u(av.w, uv.w, acc[j]);
        }
      }
      // fp16 partials: Pf[cur] word (w>>1)*512 + 64j + l, half (w&1)
      _Float16* pfh = (_Float16*)Pf[cur];
#pragma unroll
      for (int j = 0; j < 8; j++)
        pfh[(((w >> 1) * 512 + 64 * j + l) << 1) | (w & 1)] = (_Float16)acc[j];
    }
    __syncthreads();   // THE barrier: Pf(cur) + red(cur) visible

    // Owner phase: lane lo of wave w owns state i_own = 32w + lo.
    {
      int gexpw = 19;
      if (t) {
        // consume sigma of step t-1 (uniform across all threads)
        const float4* rp = (const float4*)red[cur];
        float4 r0 = rp[0], r1 = rp[1], r2 = rp[2], r3 = rp[3];
        float sp = (((r0.x + r0.y) + (r0.z + r0.w)) + ((r1.x + r1.y) + (r1.z + r1.w)))
                 + (((r2.x + r2.y) + (r2.z + r2.w)) + ((r3.x + r3.y) + (r3.z + r3.w)));
        float ls = __log2f(sp);
        int e = ((__builtin_bit_cast(int, sp) >> 23) & 0xff) - 126;  // sp=m*2^e
        c += ls - Dlog;
        Dlog = (float)gexp_prev + ls;
        gexpw = 19 - gexp_prev - e;
      }
      if (owner) {
        float em = __expf(epre - lse_i);
        float raw;
        if (t) {
          const unsigned int* pf = Pf[cur];
          float ssum = 0.f;
#pragma unroll
          for (int kk2 = 0; kk2 < 8; kk2++) {
            h2v pv = __builtin_bit_cast(h2v, pf[kk2 * 512 + i_own]);
            ssum += (float)pv.x + (float)pv.y;
          }
          raw = ssum * em;
        } else {
          raw = pi_i * em;
        }
        // u[i_own]: consumed only by this wave's dot(t+1) -- no barrier
        ((_Float16*)ubuf)[i_own] = (_Float16)ldexpf(raw, gexpw);
        // sigma partial over this wave's 32 owner lanes
        float s = raw;
        s += __shfl_xor(s, 16, 64);
        s += __shfl_xor(s, 8, 64);
        s += __shfl_xor(s, 4, 64);
        s += __shfl_xor(s, 2, 64);
        s += __shfl_xor(s, 1, 64);
        if (lo == 0) red[nxt][w] = s;
      }
      gexp_prev = gexpw;
    }
    cur = nxt;
  }
  // final: consume last step's sigma (written at owner(Tb-1) to red[cur])
  __syncthreads();
  {
    const float4* rp = (const float4*)red[cur];
    float4 r0 = rp[0], r1 = rp[1], r2 = rp[2], r3 = rp[3];
    float sp = (((r0.x + r0.y) + (r0.z + r0.w)) + ((r1.x + r1.y) + (r1.z + r1.w)))
             + (((r2.x + r2.y) + (r2.z + r2.w)) + ((r3.x + r3.y) + (r3.z + r3.w)));
    c += __log2f(sp) - Dlog;
  }
  if (tid == 0) out[b] = c * 0.69314718055994530942f;
}

extern "C" void kernel_launch(void* const* d_in, const int* in_sizes, int n_in,
                              void* d_out, int out_size, void* d_ws, size_t ws_size,
                              hipStream_t stream) {
  const float* pi = (const float*)d_in[0];
  const float* A  = (const float*)d_in[1];
  const float* E  = (const float*)d_in[2];
  const int*   x  = (const int*)d_in[3];
  const int*   T  = (const int*)d_in[4];
  float* out = (float*)d_out;

  char* ws = (char*)d_ws;
  float*        pi_sm = (float*)(ws + 0);
  float*        lseA  = (float*)(ws + 2048);
  float*        lseE  = (float*)(ws + 4096);
  unsigned int* Apk   = (unsigned int*)(ws + 6144);  // 512*512 fp16 = 512 KB

  hipLaunchKernelGGL(k_pi,      dim3(1),   dim3(512),  0, stream, pi, pi_sm);
  hipLaunchKernelGGL(k_colLse,  dim3(512), dim3(256),  0, stream, A, lseA);
  hipLaunchKernelGGL(k_rowLseE, dim3(512), dim3(256),  0, stream, E, lseE);
  hipLaunchKernelGGL(k_pack,    dim3(256), dim3(512),  0, stream, A, lseA, Apk);
  hipLaunchKernelGGL(k_fwd,     dim3(64),  dim3(1024), 0, stream,
                     E, x, T, pi_sm, lseE, (const uint4*)Apk, out);
}